// Round 4
// baseline (951.772 us; speedup 1.0000x reference)
//
#include <hip/hip_runtime.h>

#define NN  100000
#define NNP 100096   // NN padded to multiple of 32/128
#define NE  1600000
#define DD  128

typedef __attribute__((ext_vector_type(8))) short bf16x8;
typedef __attribute__((ext_vector_type(4))) float f32x4;

__device__ __forceinline__ float bf2f(unsigned short u){
  union { unsigned int i; float f; } v; v.i = ((unsigned int)u) << 16; return v.f;
}
__device__ __forceinline__ unsigned short f2bf(float f){
  union { float f; unsigned int i; } v; v.f = f;
  unsigned int u = v.i;
  return (unsigned short)((u + 0x7fffu + ((u >> 16) & 1u)) >> 16);
}
__device__ __forceinline__ unsigned int cvt_pk_bf16(float lo, float hi){
  unsigned int r;
  asm("v_cvt_pk_bf16_f32 %0, %1, %2" : "=v"(r) : "v"(lo), "v"(hi));
  return r;
}

// ---------- all 8 weight matrices f32 -> bf16 in one launch ----------
struct WPtrs { const float* w[8]; };
__global__ __launch_bounds__(256) void cvt_w_all(WPtrs wp, unsigned short* __restrict__ o){
  int t = blockIdx.x * 256 + threadIdx.x;     // 65536 threads
  int m = t >> 13, i = t & 8191;
  float2 v = ((const float2*)wp.w[m])[i];
  ((unsigned int*)o)[t] = cvt_pk_bf16(v.x, v.y);
}

// ---------- CSR build ----------
__global__ __launch_bounds__(256) void count_deg(const int* __restrict__ dst,
                                                 int* __restrict__ deg, int n){
  int t = blockIdx.x * 256 + threadIdx.x;
  if (t < n) atomicAdd(&deg[dst[t]], 1);
}

#define SCAN_CHUNK 1024
__global__ __launch_bounds__(256) void partial_sums(const int* __restrict__ deg,
                                                    int* __restrict__ partials, int n){
  __shared__ int lds[256];
  int t = threadIdx.x;
  int base = blockIdx.x * SCAN_CHUNK + t * 4;
  int s = 0;
  #pragma unroll
  for (int i = 0; i < 4; ++i){ int idx = base + i; s += (idx < n) ? deg[idx] : 0; }
  lds[t] = s; __syncthreads();
  for (int off = 128; off > 0; off >>= 1){
    if (t < off) lds[t] += lds[t + off];
    __syncthreads();
  }
  if (t == 0) partials[blockIdx.x] = lds[0];
}

__global__ void scan_partials(int* partials, int nb){
  if (threadIdx.x == 0 && blockIdx.x == 0){
    int acc = 0;
    for (int i = 0; i < nb; ++i){ int v = partials[i]; partials[i] = acc; acc += v; }
  }
}

__global__ __launch_bounds__(256) void scan_block(const int* __restrict__ deg,
                                                  const int* __restrict__ partials,
                                                  int* __restrict__ row_start, int n){
  __shared__ int lds[256];
  int t = threadIdx.x;
  int base = blockIdx.x * SCAN_CHUNK + t * 4;
  int v[4]; int s = 0;
  #pragma unroll
  for (int i = 0; i < 4; ++i){ int idx = base + i; v[i] = (idx < n) ? deg[idx] : 0; s += v[i]; }
  lds[t] = s; __syncthreads();
  for (int off = 1; off < 256; off <<= 1){
    int x = (t >= off) ? lds[t - off] : 0;
    __syncthreads();
    lds[t] += x;
    __syncthreads();
  }
  int excl = ((t == 0) ? 0 : lds[t - 1]) + partials[blockIdx.x];
  #pragma unroll
  for (int i = 0; i < 4; ++i){ int idx = base + i; if (idx < n) row_start[idx] = excl; excl += v[i]; }
}

__global__ __launch_bounds__(256) void fill_csr(const int* __restrict__ src,
                                                const int* __restrict__ dst,
                                                const int* __restrict__ row_start,
                                                int* __restrict__ cursor,
                                                int* __restrict__ csr, int n){
  int t = blockIdx.x * 256 + threadIdx.x;
  if (t < n){
    int d = dst[t];
    int pos = atomicAdd(&cursor[d], 1);
    csr[row_start[d] + pos] = src[t];
  }
}

// ---------- h0 = bf16(item_emb[x]) ----------
__global__ __launch_bounds__(256) void gather_h0(const int* __restrict__ x,
                                                 const float* __restrict__ emb,
                                                 unsigned short* __restrict__ h, int n){
  int t = blockIdx.x * 256 + threadIdx.x;          // n*64 threads, 2 feats each
  if (t >= n * 64) return;
  int node = t >> 6, p = t & 63;
  int s = x[node];
  float2 v = *(const float2*)(emb + (size_t)s * DD + p * 2);
  ((unsigned int*)h)[t] = cvt_pk_bf16(v.x, v.y);
}

// ---------- stage one 128x128 bf16 matrix into LDS, k-chunk-major ----------
// layout: sB[(kc*128 + col)*8 .. +8] holds W[col][kc*8 .. kc*8+8]
__device__ __forceinline__ void stage_mat(const unsigned short* __restrict__ Bg,
                                          unsigned short* sB){
  int t = threadIdx.x; // 256
  #pragma unroll
  for (int it = 0; it < 8; ++it){
    int idx = it * 256 + t;               // 0..2047 = kc*128 + col
    int kc = idx >> 7, col = idx & 127;
    uint4 v = *(const uint4*)(Bg + (size_t)col * DD + kc * 8);
    *(uint4*)(sB + (size_t)idx * 8) = v;
  }
}

// ================= fused layer: aggregate + dual GEMM (+ final GEMM) =========
// block = 256 threads (4 waves), 32 nodes/block.
// LDS: sW 32KB (staged Wl, then Wr, then Wfin) + sMean 8KB (swizzled).
// swizzle: uint index u within a node-row -> u ^ ((node&7)<<2)
template<int FINAL>
__global__ __launch_bounds__(256, 4) void fused_layer(
    const unsigned short* __restrict__ h_in,
    const int* __restrict__ csr, const int* __restrict__ row_st,
    const int* __restrict__ deg,
    const unsigned short* __restrict__ Wl, const unsigned short* __restrict__ Wr,
    const float* __restrict__ bl,
    const unsigned short* __restrict__ Wfin, const float* __restrict__ bfin,
    unsigned short* __restrict__ h_out, float* __restrict__ f_out)
{
  __shared__ unsigned short sW[16384];   // 32KB: one 128x128 bf16 matrix
  __shared__ unsigned int   sMean[2048]; // 8KB: 32 nodes x 64 uints (swizzled)

  const int tid  = threadIdx.x;
  const int w    = tid >> 6;
  const int lane = tid & 63;
  const int lr   = lane & 15, lk = lane >> 4;
  const int nodeBase = blockIdx.x * 32;

  // ---- stage Wl (loads overlap the gathers below; barrier after gather) ----
  stage_mat(Wl, sW);

  // ---- gather + mean for 8 nodes per wave ----
  const unsigned int* hp = (const unsigned int*)h_in;
  #pragma unroll 1
  for (int i = 0; i < 8; ++i){
    int n  = w * 8 + i;
    int g  = nodeBase + n;
    int st = __builtin_amdgcn_readfirstlane(row_st[g]);
    int d  = __builtin_amdgcn_readfirstlane(deg[g]);
    float a0 = 0.f, a1 = 0.f, b0 = 0.f, b1 = 0.f;
    float c0 = 0.f, c1 = 0.f, e0 = 0.f, e1 = 0.f;
    int k = 0;
    for (; k + 16 <= d; k += 16){
      int idx[16];
      #pragma unroll
      for (int q = 0; q < 16; ++q) idx[q] = csr[st + k + q];
      unsigned int vv[16];
      #pragma unroll
      for (int q = 0; q < 16; ++q) vv[q] = hp[(size_t)idx[q] * 64 + lane];
      #pragma unroll
      for (int q = 0; q < 16; q += 4){
        a0 += bf2f((unsigned short)(vv[q  ] & 0xffffu)); a1 += bf2f((unsigned short)(vv[q  ] >> 16));
        b0 += bf2f((unsigned short)(vv[q+1] & 0xffffu)); b1 += bf2f((unsigned short)(vv[q+1] >> 16));
        c0 += bf2f((unsigned short)(vv[q+2] & 0xffffu)); c1 += bf2f((unsigned short)(vv[q+2] >> 16));
        e0 += bf2f((unsigned short)(vv[q+3] & 0xffffu)); e1 += bf2f((unsigned short)(vv[q+3] >> 16));
      }
    }
    for (; k + 4 <= d; k += 4){
      int idx[4];
      #pragma unroll
      for (int q = 0; q < 4; ++q) idx[q] = csr[st + k + q];
      unsigned int vv[4];
      #pragma unroll
      for (int q = 0; q < 4; ++q) vv[q] = hp[(size_t)idx[q] * 64 + lane];
      a0 += bf2f((unsigned short)(vv[0] & 0xffffu)); a1 += bf2f((unsigned short)(vv[0] >> 16));
      b0 += bf2f((unsigned short)(vv[1] & 0xffffu)); b1 += bf2f((unsigned short)(vv[1] >> 16));
      c0 += bf2f((unsigned short)(vv[2] & 0xffffu)); c1 += bf2f((unsigned short)(vv[2] >> 16));
      e0 += bf2f((unsigned short)(vv[3] & 0xffffu)); e1 += bf2f((unsigned short)(vv[3] >> 16));
    }
    for (; k < d; ++k){
      int s = csr[st + k];
      unsigned int v = hp[(size_t)s * 64 + lane];
      a0 += bf2f((unsigned short)(v & 0xffffu)); a1 += bf2f((unsigned short)(v >> 16));
    }
    float s0 = (a0 + b0) + (c0 + e0);
    float s1 = (a1 + b1) + (c1 + e1);
    float inv = 1.0f / fmaxf((float)d, 1.0f);
    sMean[n * 64 + (lane ^ ((n & 7) << 2))] = cvt_pk_bf16(s0 * inv, s1 * inv);
  }
  __syncthreads();

  // ---- GEMM setup: wave (rh,ch): rows rh*16..+16, cols ch*64..+64 ----
  const int rh = w >> 1, ch = w & 1;
  float bv[4];
  #pragma unroll
  for (int j = 0; j < 4; ++j) bv[j] = bl[ch * 64 + j * 16 + lr];

  f32x4 acc[4];
  #pragma unroll
  for (int j = 0; j < 4; ++j) acc[j] = (f32x4){0.f, 0.f, 0.f, 0.f};

  // ---- M1: acc += mean @ Wl^T ----
  #pragma unroll
  for (int ks = 0; ks < 4; ++ks){
    bf16x8 a = *(const bf16x8*)&sMean[(rh * 16 + lr) * 64 + ((ks * 16 + lk * 4) ^ ((lr & 7) << 2))];
    #pragma unroll
    for (int j = 0; j < 4; ++j){
      bf16x8 b = *(const bf16x8*)(sW + (((ks * 4 + lk) * 128) + ch * 64 + j * 16 + lr) * 8);
      acc[j] = __builtin_amdgcn_mfma_f32_16x16x32_bf16(a, b, acc[j], 0, 0, 0);
    }
  }
  __syncthreads();
  stage_mat(Wr, sW);
  __syncthreads();

  // ---- M2: acc += h @ Wr^T (A straight from global) ----
  {
    const unsigned short* Ap = h_in + (size_t)(nodeBase + rh * 16 + lr) * DD + lk * 8;
    #pragma unroll
    for (int ks = 0; ks < 4; ++ks){
      bf16x8 a = *(const bf16x8*)(Ap + ks * 32);
      #pragma unroll
      for (int j = 0; j < 4; ++j){
        bf16x8 b = *(const bf16x8*)(sW + (((ks * 4 + lk) * 128) + ch * 64 + j * 16 + lr) * 8);
        acc[j] = __builtin_amdgcn_mfma_f32_16x16x32_bf16(a, b, acc[j], 0, 0, 0);
      }
    }
  }

  if (!FINAL){
    #pragma unroll
    for (int j = 0; j < 4; ++j){
      int col = ch * 64 + j * 16 + lr;
      #pragma unroll
      for (int r = 0; r < 4; ++r){
        size_t row = (size_t)nodeBase + rh * 16 + lk * 4 + r;
        h_out[row * DD + col] = f2bf(fmaxf(acc[j][r] + bv[j], 0.f));
      }
    }
    return;
  }

  // ---- FINAL: h3 -> LDS (reuse sMean), stage W_lin1, second GEMM ----
  __syncthreads();                 // all waves done reading sW (M2)
  #pragma unroll
  for (int j = 0; j < 4; ++j){
    int col = ch * 64 + j * 16 + lr;
    #pragma unroll
    for (int r = 0; r < 4; ++r){
      int n2 = rh * 16 + lk * 4 + r;
      float v = fmaxf(acc[j][r] + bv[j], 0.f);
      int uidx = (col >> 1) ^ ((n2 & 7) << 2);
      ((unsigned short*)sMean)[(n2 * 64 + uidx) * 2 + (col & 1)] = f2bf(v);
    }
  }
  stage_mat(Wfin, sW);
  __syncthreads();

  float bv2[4];
  #pragma unroll
  for (int j = 0; j < 4; ++j) bv2[j] = bfin[ch * 64 + j * 16 + lr];
  f32x4 acc2[4];
  #pragma unroll
  for (int j = 0; j < 4; ++j) acc2[j] = (f32x4){0.f, 0.f, 0.f, 0.f};
  #pragma unroll
  for (int ks = 0; ks < 4; ++ks){
    bf16x8 a = *(const bf16x8*)&sMean[(rh * 16 + lr) * 64 + ((ks * 16 + lk * 4) ^ ((lr & 7) << 2))];
    #pragma unroll
    for (int j = 0; j < 4; ++j){
      bf16x8 b = *(const bf16x8*)(sW + (((ks * 4 + lk) * 128) + ch * 64 + j * 16 + lr) * 8);
      acc2[j] = __builtin_amdgcn_mfma_f32_16x16x32_bf16(a, b, acc2[j], 0, 0, 0);
    }
  }
  #pragma unroll
  for (int j = 0; j < 4; ++j){
    int col = ch * 64 + j * 16 + lr;
    #pragma unroll
    for (int r = 0; r < 4; ++r){
      size_t row = (size_t)nodeBase + rh * 16 + lk * 4 + r;
      if (row < (size_t)NN)
        f_out[row * DD + col] = fmaxf(acc2[j][r] + bv2[j], 0.f);
    }
  }
}

// ---------- edge GEMM: 64-row tile per block, 16 rows/wave ----------
__global__ __launch_bounds__(256, 4) void gemm_edge4(
    const float* __restrict__ A, const unsigned short* __restrict__ Bg,
    const float* __restrict__ bias, float* __restrict__ out)
{
  __shared__ unsigned short sB[16384]; // 32KB
  stage_mat(Bg, sB);
  int w = threadIdx.x >> 6, lane = threadIdx.x & 63;
  int lr = lane & 15, lk = lane >> 4;
  size_t r0 = (size_t)blockIdx.x * 64 + (size_t)w * 16;
  const float* Ap = A + (r0 + lr) * DD + lk * 8;

  f32x4 raw[4][2];
  #pragma unroll
  for (int ks = 0; ks < 4; ++ks){
    raw[ks][0] = __builtin_nontemporal_load((const f32x4*)(Ap + ks * 32));
    raw[ks][1] = __builtin_nontemporal_load((const f32x4*)(Ap + ks * 32 + 4));
  }
  float bv[8];
  #pragma unroll
  for (int j = 0; j < 8; ++j) bv[j] = bias[j * 16 + lr];

  __syncthreads();   // staging done; vmcnt drain also lands the A loads

  f32x4 acc[8];
  #pragma unroll
  for (int j = 0; j < 8; ++j) acc[j] = (f32x4){0.f, 0.f, 0.f, 0.f};
  #pragma unroll
  for (int ks = 0; ks < 4; ++ks){
    union { bf16x8 v; unsigned int u[4]; } au;
    au.u[0] = cvt_pk_bf16(raw[ks][0][0], raw[ks][0][1]);
    au.u[1] = cvt_pk_bf16(raw[ks][0][2], raw[ks][0][3]);
    au.u[2] = cvt_pk_bf16(raw[ks][1][0], raw[ks][1][1]);
    au.u[3] = cvt_pk_bf16(raw[ks][1][2], raw[ks][1][3]);
    #pragma unroll
    for (int j = 0; j < 8; ++j){
      bf16x8 b = *(const bf16x8*)(sB + (((ks * 4 + lk) * 128) + j * 16 + lr) * 8);
      acc[j] = __builtin_amdgcn_mfma_f32_16x16x32_bf16(au.v, b, acc[j], 0, 0, 0);
    }
  }
  #pragma unroll
  for (int j = 0; j < 8; ++j)
    #pragma unroll
    for (int r = 0; r < 4; ++r){
      size_t row = r0 + lk * 4 + r;
      out[row * DD + j * 16 + lr] = fmaxf(acc[j][r] + bv[j], 0.f);
    }
}

extern "C" void kernel_launch(void* const* d_in, const int* in_sizes, int n_in,
                              void* d_out, int out_size, void* d_ws, size_t ws_size,
                              hipStream_t stream)
{
  const int*   x    = (const int*)d_in[0];
  const int*   ei   = (const int*)d_in[1];
  const int*   srcp = ei;
  const int*   dstp = ei + NE;
  const float* item = (const float*)d_in[3];
  const float* eemb = (const float*)d_in[4];
  WPtrs wp;
  wp.w[0] = (const float*)d_in[5];  // Wl1
  wp.w[1] = (const float*)d_in[7];  // Wr1
  wp.w[2] = (const float*)d_in[8];  // Wl2
  wp.w[3] = (const float*)d_in[10]; // Wr2
  wp.w[4] = (const float*)d_in[11]; // Wl3
  wp.w[5] = (const float*)d_in[13]; // Wr3
  wp.w[6] = (const float*)d_in[14]; // W_lin1
  wp.w[7] = (const float*)d_in[16]; // W_lin2
  const float* bl1 = (const float*)d_in[6];
  const float* bl2 = (const float*)d_in[9];
  const float* bl3 = (const float*)d_in[12];
  const float* bq1 = (const float*)d_in[15];
  const float* bq2 = (const float*)d_in[17];

  char* ws = (char*)d_ws;
  size_t o = 0;
  auto alloc = [&](size_t bytes) -> void* {
    void* p = ws + o;
    o += (bytes + 255) & ~(size_t)255;
    return p;
  };
  unsigned short* wbf      = (unsigned short*)alloc(8 * 16384 * 2);
  int*            deg      = (int*)alloc((size_t)NNP * 4);   // NNP*4 = 400384, 256-aligned
  int*            cursor   = (int*)alloc((size_t)NNP * 4);
  int*            row_st   = (int*)alloc((size_t)NNP * 4);
  int*            partials = (int*)alloc(4096);
  int*            csr      = (int*)alloc((size_t)NE * 4);
  unsigned short* h_a      = (unsigned short*)alloc((size_t)NNP * DD * 2);
  unsigned short* h_b      = (unsigned short*)alloc((size_t)NNP * DD * 2);

  float* out_h = (float*)d_out;
  float* out_e = out_h + (size_t)NN * DD;

  // zero deg + cursor + row_st (three adjacent 400384-byte allocations)
  hipMemsetAsync(deg, 0, (size_t)NNP * 4 * 3, stream);

  cvt_w_all<<<256, 256, 0, stream>>>(wp, wbf);

  const int nb = (NN + SCAN_CHUNK - 1) / SCAN_CHUNK;      // 98
  count_deg<<<(NE + 255) / 256, 256, 0, stream>>>(dstp, deg, NE);
  partial_sums<<<nb, 256, 0, stream>>>(deg, partials, NN);
  scan_partials<<<1, 64, 0, stream>>>(partials, nb);
  scan_block<<<nb, 256, 0, stream>>>(deg, partials, row_st, NN);
  fill_csr<<<(NE + 255) / 256, 256, 0, stream>>>(srcp, dstp, row_st, cursor, csr, NE);

  gather_h0<<<(NN * 64 + 255) / 256, 256, 0, stream>>>(x, item, h_a, NN);

  const int layer_grid = NNP / 32;          // 3128

  // layer 1: h_a -> h_b
  fused_layer<0><<<layer_grid, 256, 0, stream>>>(h_a, csr, row_st, deg,
      wbf + 0*16384, wbf + 1*16384, bl1, nullptr, nullptr, h_b, nullptr);
  // layer 2: h_b -> h_a
  fused_layer<0><<<layer_grid, 256, 0, stream>>>(h_b, csr, row_st, deg,
      wbf + 2*16384, wbf + 3*16384, bl2, nullptr, nullptr, h_a, nullptr);
  // layer 3 + final linear: h_a -> out_h (f32)
  fused_layer<1><<<layer_grid, 256, 0, stream>>>(h_a, csr, row_st, deg,
      wbf + 4*16384, wbf + 5*16384, bl3, wbf + 6*16384, bq1, nullptr, out_h);

  // edge linear -> f32 out
  gemm_edge4<<<NE / 64, 256, 0, stream>>>(eemb, wbf + 7*16384, bq2, out_e);
}